// Round 10
// baseline (6317.289 us; speedup 1.0000x reference)
//
#include <hip/hip_runtime.h>

#define NROWS 262144
#define DDIM 64
#define QSTAGES 8
#define KCODES 1024

// norms: np.sum(cb*cb, -1) — numpy pairwise_sum, baseline npyv SSE 4-lane path
// for n=64:
//   sq[d]    = RN(c_d * c_d)                       (cb*cb ufunc temp)
//   r[m][j]  = RN(sq[4m+j] + sq[32+4m+j])          (8 vec accs, 1 add pass)
//   L[j]     = ((r0j+r1j)+(r2j+r3j)) + ((r4j+r5j)+(r6j+r7j))
//   norm     = (L0+L1) + (L2+L3)                   (two SSE3 hadds)
__device__ float g_norm32[QSTAGES * KCODES];

__global__ __launch_bounds__(256) void rvq_norms_kernel(
    const float* __restrict__ cb) {
    int c = blockIdx.x * blockDim.x + threadIdx.x;
    if (c >= QSTAGES * KCODES) return;
    const float* p = cb + (size_t)c * DDIM;
    float sq[DDIM];
    #pragma unroll
    for (int d = 0; d < DDIM; ++d) sq[d] = __fmul_rn(p[d], p[d]);
    float r[8][4];
    #pragma unroll
    for (int m = 0; m < 8; ++m)
        #pragma unroll
        for (int j = 0; j < 4; ++j)
            r[m][j] = __fadd_rn(sq[4 * m + j], sq[32 + 4 * m + j]);
    float L[4];
    #pragma unroll
    for (int j = 0; j < 4; ++j)
        L[j] = __fadd_rn(
            __fadd_rn(__fadd_rn(r[0][j], r[1][j]), __fadd_rn(r[2][j], r[3][j])),
            __fadd_rn(__fadd_rn(r[4][j], r[5][j]), __fadd_rn(r[6][j], r[7][j])));
    g_norm32[c] = __fadd_rn(__fadd_rn(L[0], L[1]), __fadd_rn(L[2], L[3]));
}

// One thread per row. Twin of the numpy reference:
//   r   = x - quantized              (elementwise fp32 sub)
//   dot = BLAS sgemm micro-kernel:   acc=0; acc=fma(r[d],c[d],acc), d ascending
//   d_k = (-2.0f*dot) + norm_k       (exact *-2, one fp32 RN add)
//   idx = first minimum (strict <, ascending k)   [np.argmin tiebreak]
//   quantized += cb[idx]             (elementwise fp32 add)
__global__ __launch_bounds__(256) void rvq_main_kernel(
    const float* __restrict__ x,
    const float* __restrict__ cb,
    float* __restrict__ out_enc,   // [N, Q] indices stored as float
    float* __restrict__ out_q) {   // [N, D] quantized
    const int row = blockIdx.x * blockDim.x + threadIdx.x;
    const float4* xr4 = reinterpret_cast<const float4*>(x + (size_t)row * DDIM);

    float qacc[DDIM];              // fp32 quantized accumulator (mirrors ref)
    #pragma unroll
    for (int i = 0; i < DDIM; ++i) qacc[i] = 0.0f;

    float enc[QSTAGES];

    for (int q = 0; q < QSTAGES; ++q) {
        // r = x - quantized, elementwise fp32 (x re-streamed, L2/L3-hot)
        float rf[DDIM];
        #pragma unroll
        for (int i = 0; i < DDIM / 4; ++i) {
            float4 v = xr4[i];
            rf[4 * i + 0] = __fsub_rn(v.x, qacc[4 * i + 0]);
            rf[4 * i + 1] = __fsub_rn(v.y, qacc[4 * i + 1]);
            rf[4 * i + 2] = __fsub_rn(v.z, qacc[4 * i + 2]);
            rf[4 * i + 3] = __fsub_rn(v.w, qacc[4 * i + 3]);
        }

        const float* cq = cb + (size_t)q * KCODES * DDIM;
        const float* nq = g_norm32 + q * KCODES;

        float best = 3.4e38f;
        int bidx = 0;

        for (int k = 0; k < KCODES; ++k) {
            const float* c = cq + (size_t)k * DDIM;   // wave-uniform -> s_load
            // sgemm semantics: single accumulator, sequential ascending FMA.
            // fma(r0,c0,0) == RN(r0*c0): matches the zeroed C register.
            float acc = 0.0f;
            #pragma unroll
            for (int d = 0; d < DDIM; ++d)
                acc = __builtin_fmaf(rf[d], c[d], acc);
            float dist = __fadd_rn(__fmul_rn(-2.0f, acc), nq[k]);
            if (dist < best) { best = dist; bidx = k; }   // first-min
        }

        // quantized = quantized + cb[idx], elementwise fp32
        const float4* csel = reinterpret_cast<const float4*>(
            cq + (size_t)bidx * DDIM);
        #pragma unroll
        for (int i = 0; i < DDIM / 4; ++i) {
            float4 v = csel[i];
            qacc[4 * i + 0] = __fadd_rn(qacc[4 * i + 0], v.x);
            qacc[4 * i + 1] = __fadd_rn(qacc[4 * i + 1], v.y);
            qacc[4 * i + 2] = __fadd_rn(qacc[4 * i + 2], v.z);
            qacc[4 * i + 3] = __fadd_rn(qacc[4 * i + 3], v.w);
        }

        enc[q] = (float)bidx;
    }

    // encoded [N, Q] row-major
    #pragma unroll
    for (int q = 0; q < QSTAGES; ++q)
        out_enc[(size_t)row * QSTAGES + q] = enc[q];

    // quantized output = fp32 accumulator (bit-identical to reference)
    float4* oq = reinterpret_cast<float4*>(out_q + (size_t)row * DDIM);
    #pragma unroll
    for (int i = 0; i < DDIM / 4; ++i) {
        float4 w;
        w.x = qacc[4 * i + 0];
        w.y = qacc[4 * i + 1];
        w.z = qacc[4 * i + 2];
        w.w = qacc[4 * i + 3];
        oq[i] = w;
    }
}

extern "C" void kernel_launch(void* const* d_in, const int* in_sizes, int n_in,
                              void* d_out, int out_size, void* d_ws, size_t ws_size,
                              hipStream_t stream) {
    const float* x  = (const float*)d_in[0];   // [N, D]
    const float* cb = (const float*)d_in[1];   // [Q, K, D]

    float* out_enc = (float*)d_out;                       // [N, Q]
    float* out_q   = out_enc + (size_t)NROWS * QSTAGES;   // [N, D]

    rvq_norms_kernel<<<(QSTAGES * KCODES + 255) / 256, 256, 0, stream>>>(cb);
    rvq_main_kernel<<<NROWS / 256, 256, 0, stream>>>(x, cb, out_enc, out_q);
}